// Round 15
// baseline (197.167 us; speedup 1.0000x reference)
//
#include <hip/hip_runtime.h>
#include <math.h>

#define F_DIM 512
#define H_DIM 128
#define C_DIM 40
#define EPS_F 0.3f
#define NBLK 256   // partition blocks

typedef float f32x4 __attribute__((ext_vector_type(4)));
typedef unsigned int u32x4 __attribute__((ext_vector_type(4)));
typedef __bf16 bf16x8 __attribute__((ext_vector_type(8)));
typedef unsigned short ushort_t;
typedef unsigned char uchar_t;

__device__ inline float bflo(unsigned t) { return __builtin_bit_cast(float, t << 16); }
__device__ inline float bfhi(unsigned t) { return __builtin_bit_cast(float, t & 0xffff0000u); }
__device__ inline unsigned short f2bf(float f) {
  unsigned u = __builtin_bit_cast(unsigned, f);
  u = (u + 0x7fffu + ((u >> 16) & 1u)) >> 16;
  return (unsigned short)u;
}
__device__ inline unsigned pack2bf(float a, float b) {
  unsigned ua = __builtin_bit_cast(unsigned, a);
  unsigned ub = __builtin_bit_cast(unsigned, b);
  ua = (ua + 0x7fffu + ((ua >> 16) & 1u)) >> 16;
  ub = (ub + 0x7fffu + ((ub >> 16) & 1u)) >> 16;
  return ua | (ub << 16);
}
// fast tanh: 1 - 2/(e^{2x}+1); exact limits, ~1e-6 err
__device__ inline float fast_tanh(float x) {
  float e = __expf(2.0f * x);
  return 1.0f - 2.0f / (e + 1.0f);
}

// ---------------- CSR build: 3 kernels, LDS-scope atomics only ----------------

__global__ __launch_bounds__(256) void part_count(const int* __restrict__ row,
    const int* __restrict__ col, int* __restrict__ blkhist, int E, int nbkt, int chunk) {
  __shared__ int ch[256], rh[256];
  int t = threadIdx.x, b = blockIdx.x;
  ch[t] = 0; rh[t] = 0;
  __syncthreads();
  int s = b * chunk, e = min(E, s + chunk);
  for (int i = s + t; i < e; i += 256) {
    atomicAdd(&ch[((unsigned)col[i]) >> 8], 1);
    atomicAdd(&rh[((unsigned)row[i]) >> 8], 1);
  }
  __syncthreads();
  if (t < nbkt) {
    blkhist[t * NBLK + b] = ch[t];
    blkhist[(nbkt + t) * NBLK + b] = rh[t];
  }
}

__global__ __launch_bounds__(256) void part_scatter(const int* __restrict__ row,
    const int* __restrict__ col, const int* __restrict__ blkhist,
    int* __restrict__ bktbase, unsigned* __restrict__ colpart,
    uchar_t* __restrict__ rowpart, int E, int nbkt, int chunk) {
  __shared__ int sbase[400];
  __shared__ int stot[400];
  __shared__ int psum[256];
  __shared__ int sc[400];
  __shared__ int coff[400];
  int t = threadIdx.x, b = blockIdx.x;
  int nrows = 2 * nbkt;
  for (int rr = t; rr < nrows; rr += 256) {
    const int* rp = &blkhist[rr * NBLK];
    int pre = 0, tot = 0;
    for (int i = 0; i < NBLK; ++i) {
      int v = rp[i];
      pre += (i < b) ? v : 0;
      tot += v;
    }
    sbase[rr] = pre; stot[rr] = tot;
  }
  __syncthreads();
  int e0 = (2 * t     < nrows) ? stot[2 * t]     : 0;
  int e1 = (2 * t + 1 < nrows) ? stot[2 * t + 1] : 0;
  psum[t] = e0 + e1;
  __syncthreads();
  for (int off = 1; off < 256; off <<= 1) {
    int add = (t >= off) ? psum[t - off] : 0;
    __syncthreads();
    psum[t] += add;
    __syncthreads();
  }
  int pex = (t == 0) ? 0 : psum[t - 1];
  if (2 * t < nrows)     sc[2 * t]     = pex + sbase[2 * t];
  if (2 * t + 1 < nrows) sc[2 * t + 1] = pex + e0 + sbase[2 * t + 1];
  if (b == 0) {
    if (2 * t < nrows)     bktbase[2 * t]     = pex;
    if (2 * t + 1 < nrows) bktbase[2 * t + 1] = pex + e0;
    if (t == 0) bktbase[nrows] = 2 * E;
  }
  for (int rr = t; rr < nrows; rr += 256) coff[rr] = 0;
  __syncthreads();
  int s = b * chunk, e = min(E, s + chunk);
  for (int i = s + t; i < e; i += 256) {
    unsigned c = (unsigned)col[i], r = (unsigned)row[i];
    int bc = (int)(c >> 8), br = (int)(r >> 8);
    int pc = sc[bc] + atomicAdd(&coff[bc], 1);
    colpart[pc] = (r << 8) | (c & 255u);
    int pr = sc[nbkt + br] + atomicAdd(&coff[nbkt + br], 1) - E;
    rowpart[pr] = (uchar_t)(r & 255u);
  }
}

__global__ __launch_bounds__(256) void bucket_both(const unsigned* __restrict__ colpart,
    const uchar_t* __restrict__ rowpart, const int* __restrict__ bktbase,
    int* __restrict__ col_ptr, int* __restrict__ csr_src,
    float* __restrict__ nd, int N, int E, int nbkt) {
  __shared__ int cnt[256], ex[256], off[256];
  int t = threadIdx.x, bb = blockIdx.x;
  if (bb < nbkt) {
    int bkt = bb;
    int s = bktbase[bkt], e = bktbase[bkt + 1];
    cnt[t] = 0; off[t] = 0;
    __syncthreads();
    for (int i = s + t; i < e; i += 256)
      atomicAdd(&cnt[(int)(colpart[i] & 255u)], 1);
    __syncthreads();
    ex[t] = cnt[t];
    __syncthreads();
    for (int o = 1; o < 256; o <<= 1) {
      int v = (t >= o) ? ex[t - o] : 0;
      __syncthreads();
      ex[t] += v;
      __syncthreads();
    }
    int excl = (t == 0) ? 0 : ex[t - 1];
    __syncthreads();
    ex[t] = excl;
    __syncthreads();
    int node = bkt * 256 + t;
    if (node < N) col_ptr[node] = s + ex[t];
    if (bkt == 0 && t == 0) col_ptr[N] = E;
    for (int i = s + t; i < e; i += 256) {
      unsigned p = colpart[i];
      int lb = (int)(p & 255u);
      int dst = s + ex[lb] + atomicAdd(&off[lb], 1);
      csr_src[dst] = (int)(p >> 8);
    }
  } else {
    int bkt = bb - nbkt;
    int s = bktbase[nbkt + bkt] - E, e = bktbase[nbkt + bkt + 1] - E;
    cnt[t] = 0;
    __syncthreads();
    for (int i = s + t; i < e; i += 256)
      atomicAdd(&cnt[(int)rowpart[i]], 1);
    __syncthreads();
    int node = bkt * 256 + t;
    if (node < N) {
      int d = cnt[t] < 1 ? 1 : cnt[t];
      nd[node] = 1.0f / sqrtf((float)d);
    }
  }
}

// ---------------- GEMM1 (bf16 MFMA) + fused gate0, T14 software pipeline ----------------
// BM=64, BN=128, BK=64. Loads for tile k+1 issued BEFORE MFMA of tile k;
// conversion+LDS store happens a full phase later (latency hidden).

__global__ __launch_bounds__(256) void gemm1_mfma(const float* __restrict__ x,
    const float* __restrict__ w, const float* __restrict__ b,
    const float* __restrict__ gwl, const float* __restrict__ gb,
    const float* __restrict__ nd,
    ushort_t* __restrict__ hbf, float2* __restrict__ pack0,
    float* __restrict__ s2a, int N) {
  __shared__ u32x4 AsBuf[512];    // 64 rows * 128 B
  __shared__ u32x4 BsBuf[1024];   // 128 rows * 128 B
  char* Asc = (char*)AsBuf;
  char* Bsc = (char*)BsBuf;

  int t = threadIdx.x;
  int lane = t & 63;
  int wid = t >> 6;
  int wm = wid >> 1;
  int wn = wid & 1;
  int m0 = blockIdx.x * 64;
  int ql = lane & 15;

  f32x4 acc[2][4];
#pragma unroll
  for (int i = 0; i < 2; ++i)
#pragma unroll
    for (int j = 0; j < 4; ++j) acc[i][j] = (f32x4){0.f, 0.f, 0.f, 0.f};

  float bias[4], g1v[4], g2v[4];
#pragma unroll
  for (int j = 0; j < 4; ++j) {
    int c = wn * 64 + j * 16 + ql;
    bias[j] = b[c];
    g1v[j] = gwl[c];
    g2v[j] = gwl[H_DIM + c];
  }

  // staging registers for one K-tile
  f32x4 ra[4], rb[8];

  auto issue_loads = [&](int kk) {
#pragma unroll
    for (int q = 0; q < 2; ++q) {
      int c = q * 256 + t;
      int row = c >> 3, kc = c & 7;
      int gm = m0 + row;
      ra[2 * q] = (f32x4){0.f, 0.f, 0.f, 0.f};
      ra[2 * q + 1] = (f32x4){0.f, 0.f, 0.f, 0.f};
      if (gm < N) {
        const float* src = &x[(size_t)gm * F_DIM + kk + kc * 8];
        ra[2 * q] = *(const f32x4*)src;
        ra[2 * q + 1] = *(const f32x4*)(src + 4);
      }
    }
#pragma unroll
    for (int q = 0; q < 4; ++q) {
      int c = q * 256 + t;
      int row = c >> 3, kc = c & 7;
      const float* src = &w[(size_t)row * F_DIM + kk + kc * 8];
      rb[2 * q] = *(const f32x4*)src;
      rb[2 * q + 1] = *(const f32x4*)(src + 4);
    }
  };

  auto store_lds = [&]() {
#pragma unroll
    for (int q = 0; q < 2; ++q) {
      int c = q * 256 + t;
      int row = c >> 3, kc = c & 7;
      u32x4 pk;
      pk[0] = pack2bf(ra[2 * q][0], ra[2 * q][1]);
      pk[1] = pack2bf(ra[2 * q][2], ra[2 * q][3]);
      pk[2] = pack2bf(ra[2 * q + 1][0], ra[2 * q + 1][1]);
      pk[3] = pack2bf(ra[2 * q + 1][2], ra[2 * q + 1][3]);
      *(u32x4*)(Asc + row * 128 + ((kc ^ (row & 7)) << 4)) = pk;
    }
#pragma unroll
    for (int q = 0; q < 4; ++q) {
      int c = q * 256 + t;
      int row = c >> 3, kc = c & 7;
      u32x4 pk;
      pk[0] = pack2bf(rb[2 * q][0], rb[2 * q][1]);
      pk[1] = pack2bf(rb[2 * q][2], rb[2 * q][3]);
      pk[2] = pack2bf(rb[2 * q + 1][0], rb[2 * q + 1][1]);
      pk[3] = pack2bf(rb[2 * q + 1][2], rb[2 * q + 1][3]);
      *(u32x4*)(Bsc + row * 128 + ((kc ^ (row & 7)) << 4)) = pk;
    }
  };

  issue_loads(0);
  for (int kk = 0; kk < F_DIM; kk += 64) {
    store_lds();          // consumes ra/rb (waits on loads issued a phase ago)
    __syncthreads();
    if (kk + 64 < F_DIM) issue_loads(kk + 64);   // fire-and-forget into regs
#pragma unroll
    for (int kh = 0; kh < 2; ++kh) {
      bf16x8 af[2], bfr[4];
      int kc = kh * 4 + (lane >> 4);
#pragma unroll
      for (int i = 0; i < 2; ++i) {
        int row = wm * 32 + i * 16 + ql;
        af[i] = *(const bf16x8*)(Asc + row * 128 + ((kc ^ (row & 7)) << 4));
      }
#pragma unroll
      for (int j = 0; j < 4; ++j) {
        int row = wn * 64 + j * 16 + ql;
        bfr[j] = *(const bf16x8*)(Bsc + row * 128 + ((kc ^ (row & 7)) << 4));
      }
#pragma unroll
      for (int i = 0; i < 2; ++i)
#pragma unroll
        for (int j = 0; j < 4; ++j)
          acc[i][j] = __builtin_amdgcn_mfma_f32_16x16x32_bf16(af[i], bfr[j], acc[i][j], 0, 0, 0);
    }
    __syncthreads();
  }

  // epilogue: write h0 (bf16) + fused gate0 partials
  float gp1[2][4], gp2[2][4];
#pragma unroll
  for (int i = 0; i < 2; ++i)
#pragma unroll
    for (int r = 0; r < 4; ++r) { gp1[i][r] = 0.f; gp2[i][r] = 0.f; }

#pragma unroll
  for (int i = 0; i < 2; ++i) {
    int rbase = m0 + wm * 32 + i * 16 + ((lane >> 4) * 4);
#pragma unroll
    for (int j = 0; j < 4; ++j) {
      int col = wn * 64 + j * 16 + ql;
#pragma unroll
      for (int r = 0; r < 4; ++r) {
        int gr = rbase + r;
        float o = fmaxf(acc[i][j][r] + bias[j], 0.f);
        if (gr < N) hbf[(size_t)gr * H_DIM + col] = f2bf(o);
        gp1[i][r] = fmaf(o, g1v[j], gp1[i][r]);
        gp2[i][r] = fmaf(o, g2v[j], gp2[i][r]);
      }
    }
  }
#pragma unroll
  for (int i = 0; i < 2; ++i)
#pragma unroll
    for (int r = 0; r < 4; ++r) {
#pragma unroll
      for (int m = 1; m < 16; m <<= 1) {
        gp1[i][r] += __shfl_xor(gp1[i][r], m);
        gp2[i][r] += __shfl_xor(gp2[i][r], m);
      }
    }
  float* pgA = (float*)AsBuf;
  float* pgB = (float*)AsBuf + 128;
  if (ql == 0) {
#pragma unroll
    for (int i = 0; i < 2; ++i)
#pragma unroll
      for (int r = 0; r < 4; ++r) {
        int lr = wm * 32 + i * 16 + (lane >> 4) * 4 + r;
        pgA[lr * 2 + wn] = gp1[i][r];
        pgB[lr * 2 + wn] = gp2[i][r];
      }
  }
  __syncthreads();
  if (t < 64) {
    int gr = m0 + t;
    if (gr < N) {
      float p1 = pgA[t * 2] + pgA[t * 2 + 1];
      float p2 = pgB[t * 2] + pgB[t * 2 + 1];
      float ndv = nd[gr];
      pack0[gr] = make_float2(p1, ndv);
      s2a[gr] = p2 + gb[0];
    }
  }
}

// ---------------- aggregation core (R8): 64-lane u32 row gathers, MLP=8 ----------------

#define AGG_CORE(HSRC)                                                          \
  float ax = 0.f, ay = 0.f;                                                     \
  {                                                                             \
    const ushort_t* HSRC_ = (HSRC);                                             \
    int p0 = col_ptr[v], p1v = col_ptr[v + 1];                                  \
    float s2v = s2pb[v];                                                        \
    for (int base = p0; base < p1v; base += 64) {                               \
      int idx = base + lane;                                                    \
      int u = 0;                                                                \
      float cf = 0.f;                                                           \
      if (idx < p1v) {                                                          \
        u = csr_src[idx];                                                       \
        float2 pk = pack[u];                                                    \
        cf = fast_tanh(pk.x + s2v) * pk.y * ndv;                                \
      }                                                                         \
      int cnt = p1v - base;                                                     \
      if (cnt > 64) cnt = 64;                                                   \
      int j = 0;                                                                \
      for (; j + 8 <= cnt; j += 8) {                                            \
        int u0 = __shfl(u, j + 0), u1 = __shfl(u, j + 1);                       \
        int u2 = __shfl(u, j + 2), u3 = __shfl(u, j + 3);                       \
        int u4 = __shfl(u, j + 4), u5 = __shfl(u, j + 5);                       \
        int u6 = __shfl(u, j + 6), u7 = __shfl(u, j + 7);                       \
        unsigned t0 = *(const unsigned*)&HSRC_[(size_t)u0 * H_DIM + lane * 2];  \
        unsigned t1 = *(const unsigned*)&HSRC_[(size_t)u1 * H_DIM + lane * 2];  \
        unsigned t2 = *(const unsigned*)&HSRC_[(size_t)u2 * H_DIM + lane * 2];  \
        unsigned t3 = *(const unsigned*)&HSRC_[(size_t)u3 * H_DIM + lane * 2];  \
        unsigned t4 = *(const unsigned*)&HSRC_[(size_t)u4 * H_DIM + lane * 2];  \
        unsigned t5 = *(const unsigned*)&HSRC_[(size_t)u5 * H_DIM + lane * 2];  \
        unsigned t6 = *(const unsigned*)&HSRC_[(size_t)u6 * H_DIM + lane * 2];  \
        unsigned t7 = *(const unsigned*)&HSRC_[(size_t)u7 * H_DIM + lane * 2];  \
        float c0 = __shfl(cf, j + 0), c1 = __shfl(cf, j + 1);                   \
        float c2 = __shfl(cf, j + 2), c3 = __shfl(cf, j + 3);                   \
        float c4 = __shfl(cf, j + 4), c5 = __shfl(cf, j + 5);                   \
        float c6 = __shfl(cf, j + 6), c7 = __shfl(cf, j + 7);                   \
        ax = fmaf(c0, bflo(t0), ax); ay = fmaf(c0, bfhi(t0), ay);               \
        ax = fmaf(c1, bflo(t1), ax); ay = fmaf(c1, bfhi(t1), ay);               \
        ax = fmaf(c2, bflo(t2), ax); ay = fmaf(c2, bfhi(t2), ay);               \
        ax = fmaf(c3, bflo(t3), ax); ay = fmaf(c3, bfhi(t3), ay);               \
        ax = fmaf(c4, bflo(t4), ax); ay = fmaf(c4, bfhi(t4), ay);               \
        ax = fmaf(c5, bflo(t5), ax); ay = fmaf(c5, bfhi(t5), ay);               \
        ax = fmaf(c6, bflo(t6), ax); ay = fmaf(c6, bfhi(t6), ay);               \
        ax = fmaf(c7, bflo(t7), ax); ay = fmaf(c7, bfhi(t7), ay);               \
      }                                                                         \
      for (; j + 4 <= cnt; j += 4) {                                            \
        int u0 = __shfl(u, j + 0), u1 = __shfl(u, j + 1);                       \
        int u2 = __shfl(u, j + 2), u3 = __shfl(u, j + 3);                       \
        unsigned t0 = *(const unsigned*)&HSRC_[(size_t)u0 * H_DIM + lane * 2];  \
        unsigned t1 = *(const unsigned*)&HSRC_[(size_t)u1 * H_DIM + lane * 2];  \
        unsigned t2 = *(const unsigned*)&HSRC_[(size_t)u2 * H_DIM + lane * 2];  \
        unsigned t3 = *(const unsigned*)&HSRC_[(size_t)u3 * H_DIM + lane * 2];  \
        float c0 = __shfl(cf, j + 0), c1 = __shfl(cf, j + 1);                   \
        float c2 = __shfl(cf, j + 2), c3 = __shfl(cf, j + 3);                   \
        ax = fmaf(c0, bflo(t0), ax); ay = fmaf(c0, bfhi(t0), ay);               \
        ax = fmaf(c1, bflo(t1), ax); ay = fmaf(c1, bfhi(t1), ay);               \
        ax = fmaf(c2, bflo(t2), ax); ay = fmaf(c2, bfhi(t2), ay);               \
        ax = fmaf(c3, bflo(t3), ax); ay = fmaf(c3, bfhi(t3), ay);               \
      }                                                                         \
      for (; j < cnt; ++j) {                                                    \
        int uj = __shfl(u, j);                                                  \
        float cj = __shfl(cf, j);                                               \
        unsigned tj = *(const unsigned*)&HSRC_[(size_t)uj * H_DIM + lane * 2];  \
        ax = fmaf(cj, bflo(tj), ax); ay = fmaf(cj, bfhi(tj), ay);               \
      }                                                                         \
    }                                                                           \
  }

// agg layer 1: h1 = EPS*h0 + agg(h0); fused gate1 -> pack1, s2b.  Zero LDS.
__global__ __launch_bounds__(256) void agg1(const ushort_t* __restrict__ hbf,
    const float2* __restrict__ pack, const float* __restrict__ s2pb,
    const float* __restrict__ nd, const int* __restrict__ col_ptr,
    const int* __restrict__ csr_src, ushort_t* __restrict__ houtbf,
    const float* __restrict__ gwl, const float* __restrict__ gb1,
    float2* __restrict__ packo, float* __restrict__ s2o, int N) {
  int t = threadIdx.x;
  int v = blockIdx.x * 4 + (t >> 6);
  int lane = t & 63;
  if (v >= N) return;
  float ndv = nd[v];
  unsigned rv = *(const unsigned*)&hbf[(size_t)v * H_DIM + lane * 2];  // raw = h0
  AGG_CORE(hbf)
  float ox = fmaf(EPS_F, bflo(rv), ax);
  float oy = fmaf(EPS_F, bfhi(rv), ay);
  *(unsigned*)&houtbf[(size_t)v * H_DIM + lane * 2] = pack2bf(ox, oy);
  // fused gate for layer 1
  float2 g1 = *(const float2*)&gwl[lane * 2];
  float2 g2 = *(const float2*)&gwl[H_DIM + lane * 2];
  float q1 = ox * g1.x + oy * g1.y;
  float q2 = ox * g2.x + oy * g2.y;
#pragma unroll
  for (int off = 32; off > 0; off >>= 1) {
    q1 += __shfl_xor(q1, off);
    q2 += __shfl_xor(q2, off);
  }
  if (lane == 0) {
    packo[v] = make_float2(q1, ndv);
    s2o[v] = q2 + gb1[0];
  }
}

// agg layer 2: h2 = EPS*h0 + agg(h1).  Pure gather, zero LDS.
__global__ __launch_bounds__(256) void agg2(const ushort_t* __restrict__ hbf,
    const ushort_t* __restrict__ rawbf, const float2* __restrict__ pack,
    const float* __restrict__ s2pb, const float* __restrict__ nd,
    const int* __restrict__ col_ptr, const int* __restrict__ csr_src,
    ushort_t* __restrict__ houtbf, int N) {
  int t = threadIdx.x;
  int v = blockIdx.x * 4 + (t >> 6);
  int lane = t & 63;
  if (v >= N) return;
  float ndv = nd[v];
  unsigned rv = *(const unsigned*)&rawbf[(size_t)v * H_DIM + lane * 2];
  AGG_CORE(hbf)
  float ox = fmaf(EPS_F, bflo(rv), ax);
  float oy = fmaf(EPS_F, bfhi(rv), ay);
  *(unsigned*)&houtbf[(size_t)v * H_DIM + lane * 2] = pack2bf(ox, oy);
}

// ---------------- GEMM2 + log_softmax (grid-stride; weights staged once/block) ----------------

__global__ __launch_bounds__(256) void gemm2_lsm(const ushort_t* __restrict__ hbf,
    const float* __restrict__ w, const float* __restrict__ b,
    float* __restrict__ out, int N) {
  __shared__ float ws[C_DIM][129];
  __shared__ float bsh[C_DIM];
  __shared__ float hsm[4][H_DIM];
  int t = threadIdx.x;
  for (int i = t; i < C_DIM * H_DIM; i += 256) ws[i / H_DIM][i % H_DIM] = w[i];
  if (t < C_DIM) bsh[t] = b[t];
  __syncthreads();
  int wave = t >> 6, lane = t & 63;
  for (int vb = blockIdx.x * 4; vb < N; vb += gridDim.x * 4) {
    int v = vb + wave;
    bool act = v < N;
    if (act) {
      unsigned hv = *(const unsigned*)&hbf[(size_t)v * H_DIM + lane * 2];
      hsm[wave][lane * 2] = bflo(hv);
      hsm[wave][lane * 2 + 1] = bfhi(hv);
    }
    __syncthreads();
    float acc = 0.f;
    if (act && lane < C_DIM) {
#pragma unroll 8
      for (int k = 0; k < H_DIM; ++k)
        acc = fmaf(hsm[wave][k], ws[lane][k], acc);
      acc += bsh[lane];
    }
    float m = (lane < C_DIM) ? acc : -1e30f;
    for (int off = 32; off > 0; off >>= 1) m = fmaxf(m, __shfl_xor(m, off));
    float ex = (lane < C_DIM) ? expf(acc - m) : 0.f;
    float s = ex;
    for (int off = 32; off > 0; off >>= 1) s += __shfl_xor(s, off);
    float lse = m + logf(s);
    if (act && lane < C_DIM) out[(size_t)v * C_DIM + lane] = acc - lse;
    __syncthreads();
  }
}

// ---------------- launch ----------------

extern "C" void kernel_launch(void* const* d_in, const int* in_sizes, int n_in,
                              void* d_out, int out_size, void* d_ws, size_t ws_size,
                              hipStream_t stream) {
  const float* x   = (const float*)d_in[0];
  const float* t1w = (const float*)d_in[1];
  const float* t1b = (const float*)d_in[2];
  const float* t2w = (const float*)d_in[3];
  const float* t2b = (const float*)d_in[4];
  const float* gw  = (const float*)d_in[5];
  const float* gb  = (const float*)d_in[6];
  const int*   ei  = (const int*)d_in[7];
  const int N = in_sizes[0] / F_DIM;
  const int E = in_sizes[7] / 2;
  float* out = (float*)d_out;

  char* p = (char*)d_ws;
  auto take = [&](size_t bytes) {
    char* r = p;
    p += (bytes + 255) & ~(size_t)255;
    return r;
  };
  ushort_t* h0 = (ushort_t*)take((size_t)N * H_DIM * 2);
  ushort_t* h1 = (ushort_t*)take((size_t)N * H_DIM * 2);
  ushort_t* h2 = (ushort_t*)take((size_t)N * H_DIM * 2);
  float2* pack0 = (float2*)take((size_t)N * 8);
  float2* pack1 = (float2*)take((size_t)N * 8);
  float* s2a = (float*)take((size_t)N * 4);
  float* s2b = (float*)take((size_t)N * 4);
  float* nd  = (float*)take((size_t)N * 4);
  int* col_ptr = (int*)take((size_t)(N + 1) * 4);
  int* csr_src = (int*)take((size_t)E * 4);

  const int nbkt = (N + 255) >> 8;              // 196
  const int chunk = (E + NBLK - 1) / NBLK;      // 3125

  int* blkhist = (int*)take((size_t)2 * nbkt * NBLK * 4);
  int* bktbase = (int*)take((size_t)(2 * nbkt + 1) * 4);
  unsigned* colpart = (unsigned*)take((size_t)E * 4);
  uchar_t* rowpart  = (uchar_t*)take((size_t)E);

  const int* row = ei;
  const int* col = ei + E;

  part_count<<<NBLK, 256, 0, stream>>>(row, col, blkhist, E, nbkt, chunk);
  part_scatter<<<NBLK, 256, 0, stream>>>(row, col, blkhist, bktbase, colpart, rowpart, E, nbkt, chunk);
  bucket_both<<<2 * nbkt, 256, 0, stream>>>(colpart, rowpart, bktbase, col_ptr, csr_src, nd, N, E, nbkt);

  gemm1_mfma<<<(N + 63) / 64, 256, 0, stream>>>(x, t1w, t1b, gw, gb, nd, h0, pack0, s2a, N);

  int nwb = (N + 3) / 4;
  agg1<<<nwb, 256, 0, stream>>>(h0, pack0, s2a, nd, col_ptr, csr_src, h1,
                                gw + 2 * H_DIM, gb + 1, pack1, s2b, N);
  agg2<<<nwb, 256, 0, stream>>>(h1, h0, pack1, s2b, nd, col_ptr, csr_src, h2, N);

  gemm2_lsm<<<1024, 256, 0, stream>>>(h2, t2w, t2b, out, N);
}

// Round 16
// 188.312 us; speedup vs baseline: 1.0470x; 1.0470x over previous
//
#include <hip/hip_runtime.h>
#include <math.h>

#define F_DIM 512
#define H_DIM 128
#define C_DIM 40
#define EPS_F 0.3f
#define NBLK 256   // partition blocks

typedef float f32x4 __attribute__((ext_vector_type(4)));
typedef unsigned int u32x4 __attribute__((ext_vector_type(4)));
typedef __bf16 bf16x8 __attribute__((ext_vector_type(8)));
typedef unsigned short ushort_t;
typedef unsigned char uchar_t;

__device__ inline float bflo(unsigned t) { return __builtin_bit_cast(float, t << 16); }
__device__ inline float bfhi(unsigned t) { return __builtin_bit_cast(float, t & 0xffff0000u); }
__device__ inline unsigned short f2bf(float f) {
  unsigned u = __builtin_bit_cast(unsigned, f);
  u = (u + 0x7fffu + ((u >> 16) & 1u)) >> 16;
  return (unsigned short)u;
}
__device__ inline unsigned pack2bf(float a, float b) {
  unsigned ua = __builtin_bit_cast(unsigned, a);
  unsigned ub = __builtin_bit_cast(unsigned, b);
  ua = (ua + 0x7fffu + ((ua >> 16) & 1u)) >> 16;
  ub = (ub + 0x7fffu + ((ub >> 16) & 1u)) >> 16;
  return ua | (ub << 16);
}
// fast tanh: 1 - 2/(e^{2x}+1); exact limits, ~1e-6 err
__device__ inline float fast_tanh(float x) {
  float e = __expf(2.0f * x);
  return 1.0f - 2.0f / (e + 1.0f);
}

// ---------------- CSR build: 3 kernels, LDS-scope atomics only ----------------

__global__ __launch_bounds__(256) void part_count(const int* __restrict__ row,
    const int* __restrict__ col, int* __restrict__ blkhist, int E, int nbkt, int chunk) {
  __shared__ int ch[256], rh[256];
  int t = threadIdx.x, b = blockIdx.x;
  ch[t] = 0; rh[t] = 0;
  __syncthreads();
  int s = b * chunk, e = min(E, s + chunk);
  for (int i = s + t; i < e; i += 256) {
    atomicAdd(&ch[((unsigned)col[i]) >> 8], 1);
    atomicAdd(&rh[((unsigned)row[i]) >> 8], 1);
  }
  __syncthreads();
  if (t < nbkt) {
    blkhist[t * NBLK + b] = ch[t];
    blkhist[(nbkt + t) * NBLK + b] = rh[t];
  }
}

__global__ __launch_bounds__(256) void part_scatter(const int* __restrict__ row,
    const int* __restrict__ col, const int* __restrict__ blkhist,
    int* __restrict__ bktbase, unsigned* __restrict__ colpart,
    uchar_t* __restrict__ rowpart, int E, int nbkt, int chunk) {
  __shared__ int sbase[400];
  __shared__ int stot[400];
  __shared__ int psum[256];
  __shared__ int sc[400];
  __shared__ int coff[400];
  int t = threadIdx.x, b = blockIdx.x;
  int nrows = 2 * nbkt;
  for (int rr = t; rr < nrows; rr += 256) {
    const int* rp = &blkhist[rr * NBLK];
    int pre = 0, tot = 0;
    for (int i = 0; i < NBLK; ++i) {
      int v = rp[i];
      pre += (i < b) ? v : 0;
      tot += v;
    }
    sbase[rr] = pre; stot[rr] = tot;
  }
  __syncthreads();
  int e0 = (2 * t     < nrows) ? stot[2 * t]     : 0;
  int e1 = (2 * t + 1 < nrows) ? stot[2 * t + 1] : 0;
  psum[t] = e0 + e1;
  __syncthreads();
  for (int off = 1; off < 256; off <<= 1) {
    int add = (t >= off) ? psum[t - off] : 0;
    __syncthreads();
    psum[t] += add;
    __syncthreads();
  }
  int pex = (t == 0) ? 0 : psum[t - 1];
  if (2 * t < nrows)     sc[2 * t]     = pex + sbase[2 * t];
  if (2 * t + 1 < nrows) sc[2 * t + 1] = pex + e0 + sbase[2 * t + 1];
  if (b == 0) {
    if (2 * t < nrows)     bktbase[2 * t]     = pex;
    if (2 * t + 1 < nrows) bktbase[2 * t + 1] = pex + e0;
    if (t == 0) bktbase[nrows] = 2 * E;
  }
  for (int rr = t; rr < nrows; rr += 256) coff[rr] = 0;
  __syncthreads();
  int s = b * chunk, e = min(E, s + chunk);
  for (int i = s + t; i < e; i += 256) {
    unsigned c = (unsigned)col[i], r = (unsigned)row[i];
    int bc = (int)(c >> 8), br = (int)(r >> 8);
    int pc = sc[bc] + atomicAdd(&coff[bc], 1);
    colpart[pc] = (r << 8) | (c & 255u);
    int pr = sc[nbkt + br] + atomicAdd(&coff[nbkt + br], 1) - E;
    rowpart[pr] = (uchar_t)(r & 255u);
  }
}

__global__ __launch_bounds__(256) void bucket_both(const unsigned* __restrict__ colpart,
    const uchar_t* __restrict__ rowpart, const int* __restrict__ bktbase,
    int* __restrict__ col_ptr, int* __restrict__ csr_src,
    float* __restrict__ nd, int N, int E, int nbkt) {
  __shared__ int cnt[256], ex[256], off[256];
  int t = threadIdx.x, bb = blockIdx.x;
  if (bb < nbkt) {
    int bkt = bb;
    int s = bktbase[bkt], e = bktbase[bkt + 1];
    cnt[t] = 0; off[t] = 0;
    __syncthreads();
    for (int i = s + t; i < e; i += 256)
      atomicAdd(&cnt[(int)(colpart[i] & 255u)], 1);
    __syncthreads();
    ex[t] = cnt[t];
    __syncthreads();
    for (int o = 1; o < 256; o <<= 1) {
      int v = (t >= o) ? ex[t - o] : 0;
      __syncthreads();
      ex[t] += v;
      __syncthreads();
    }
    int excl = (t == 0) ? 0 : ex[t - 1];
    __syncthreads();
    ex[t] = excl;
    __syncthreads();
    int node = bkt * 256 + t;
    if (node < N) col_ptr[node] = s + ex[t];
    if (bkt == 0 && t == 0) col_ptr[N] = E;
    for (int i = s + t; i < e; i += 256) {
      unsigned p = colpart[i];
      int lb = (int)(p & 255u);
      int dst = s + ex[lb] + atomicAdd(&off[lb], 1);
      csr_src[dst] = (int)(p >> 8);
    }
  } else {
    int bkt = bb - nbkt;
    int s = bktbase[nbkt + bkt] - E, e = bktbase[nbkt + bkt + 1] - E;
    cnt[t] = 0;
    __syncthreads();
    for (int i = s + t; i < e; i += 256)
      atomicAdd(&cnt[(int)rowpart[i]], 1);
    __syncthreads();
    int node = bkt * 256 + t;
    if (node < N) {
      int d = cnt[t] < 1 ? 1 : cnt[t];
      nd[node] = 1.0f / sqrtf((float)d);
    }
  }
}

// ---------------- GEMM1 (bf16 MFMA) + fused gate0, BM=64 (R14 form) ----------------

__global__ __launch_bounds__(256) void gemm1_mfma(const float* __restrict__ x,
    const float* __restrict__ w, const float* __restrict__ b,
    const float* __restrict__ gwl, const float* __restrict__ gb,
    const float* __restrict__ nd,
    ushort_t* __restrict__ hbf, float2* __restrict__ pack0,
    float* __restrict__ s2a, int N) {
  __shared__ u32x4 AsBuf[512];    // 64 rows * 128 B
  __shared__ u32x4 BsBuf[1024];   // 128 rows * 128 B
  char* Asc = (char*)AsBuf;
  char* Bsc = (char*)BsBuf;

  int t = threadIdx.x;
  int lane = t & 63;
  int wid = t >> 6;
  int wm = wid >> 1;
  int wn = wid & 1;
  int m0 = blockIdx.x * 64;
  int ql = lane & 15;

  f32x4 acc[2][4];
#pragma unroll
  for (int i = 0; i < 2; ++i)
#pragma unroll
    for (int j = 0; j < 4; ++j) acc[i][j] = (f32x4){0.f, 0.f, 0.f, 0.f};

  float bias[4], g1v[4], g2v[4];
#pragma unroll
  for (int j = 0; j < 4; ++j) {
    int c = wn * 64 + j * 16 + ql;
    bias[j] = b[c];
    g1v[j] = gwl[c];
    g2v[j] = gwl[H_DIM + c];
  }

  for (int kk = 0; kk < F_DIM; kk += 64) {
#pragma unroll
    for (int q = 0; q < 2; ++q) {
      int c = q * 256 + t;
      int row = c >> 3, kc = c & 7;
      int gm = m0 + row;
      f32x4 v0 = {0.f, 0.f, 0.f, 0.f}, v1 = {0.f, 0.f, 0.f, 0.f};
      if (gm < N) {
        const float* src = &x[(size_t)gm * F_DIM + kk + kc * 8];
        v0 = *(const f32x4*)src;
        v1 = *(const f32x4*)(src + 4);
      }
      u32x4 pk;
      pk[0] = pack2bf(v0[0], v0[1]);
      pk[1] = pack2bf(v0[2], v0[3]);
      pk[2] = pack2bf(v1[0], v1[1]);
      pk[3] = pack2bf(v1[2], v1[3]);
      *(u32x4*)(Asc + row * 128 + ((kc ^ (row & 7)) << 4)) = pk;
    }
#pragma unroll
    for (int q = 0; q < 4; ++q) {
      int c = q * 256 + t;
      int row = c >> 3, kc = c & 7;
      const float* src = &w[(size_t)row * F_DIM + kk + kc * 8];
      f32x4 v0 = *(const f32x4*)src;
      f32x4 v1 = *(const f32x4*)(src + 4);
      u32x4 pk;
      pk[0] = pack2bf(v0[0], v0[1]);
      pk[1] = pack2bf(v0[2], v0[3]);
      pk[2] = pack2bf(v1[0], v1[1]);
      pk[3] = pack2bf(v1[2], v1[3]);
      *(u32x4*)(Bsc + row * 128 + ((kc ^ (row & 7)) << 4)) = pk;
    }
    __syncthreads();
#pragma unroll
    for (int kh = 0; kh < 2; ++kh) {
      bf16x8 af[2], bfr[4];
      int kc = kh * 4 + (lane >> 4);
#pragma unroll
      for (int i = 0; i < 2; ++i) {
        int row = wm * 32 + i * 16 + ql;
        af[i] = *(const bf16x8*)(Asc + row * 128 + ((kc ^ (row & 7)) << 4));
      }
#pragma unroll
      for (int j = 0; j < 4; ++j) {
        int row = wn * 64 + j * 16 + ql;
        bfr[j] = *(const bf16x8*)(Bsc + row * 128 + ((kc ^ (row & 7)) << 4));
      }
#pragma unroll
      for (int i = 0; i < 2; ++i)
#pragma unroll
        for (int j = 0; j < 4; ++j)
          acc[i][j] = __builtin_amdgcn_mfma_f32_16x16x32_bf16(af[i], bfr[j], acc[i][j], 0, 0, 0);
    }
    __syncthreads();
  }

  float gp1[2][4], gp2[2][4];
#pragma unroll
  for (int i = 0; i < 2; ++i)
#pragma unroll
    for (int r = 0; r < 4; ++r) { gp1[i][r] = 0.f; gp2[i][r] = 0.f; }

#pragma unroll
  for (int i = 0; i < 2; ++i) {
    int rbase = m0 + wm * 32 + i * 16 + ((lane >> 4) * 4);
#pragma unroll
    for (int j = 0; j < 4; ++j) {
      int col = wn * 64 + j * 16 + ql;
#pragma unroll
      for (int r = 0; r < 4; ++r) {
        int gr = rbase + r;
        float o = fmaxf(acc[i][j][r] + bias[j], 0.f);
        if (gr < N) hbf[(size_t)gr * H_DIM + col] = f2bf(o);
        gp1[i][r] = fmaf(o, g1v[j], gp1[i][r]);
        gp2[i][r] = fmaf(o, g2v[j], gp2[i][r]);
      }
    }
  }
#pragma unroll
  for (int i = 0; i < 2; ++i)
#pragma unroll
    for (int r = 0; r < 4; ++r) {
#pragma unroll
      for (int m = 1; m < 16; m <<= 1) {
        gp1[i][r] += __shfl_xor(gp1[i][r], m);
        gp2[i][r] += __shfl_xor(gp2[i][r], m);
      }
    }
  float* pgA = (float*)AsBuf;
  float* pgB = (float*)AsBuf + 128;
  if (ql == 0) {
#pragma unroll
    for (int i = 0; i < 2; ++i)
#pragma unroll
      for (int r = 0; r < 4; ++r) {
        int lr = wm * 32 + i * 16 + (lane >> 4) * 4 + r;
        pgA[lr * 2 + wn] = gp1[i][r];
        pgB[lr * 2 + wn] = gp2[i][r];
      }
  }
  __syncthreads();
  if (t < 64) {
    int gr = m0 + t;
    if (gr < N) {
      float p1 = pgA[t * 2] + pgA[t * 2 + 1];
      float p2 = pgB[t * 2] + pgB[t * 2 + 1];
      float ndv = nd[gr];
      pack0[gr] = make_float2(p1, ndv);
      s2a[gr] = p2 + gb[0];
    }
  }
}

// ---------------- aggregation core (R8): 64-lane u32 row gathers, MLP=8 ----------------

#define AGG_CORE(HSRC)                                                          \
  float ax = 0.f, ay = 0.f;                                                     \
  {                                                                             \
    const ushort_t* HSRC_ = (HSRC);                                             \
    int p0 = col_ptr[v], p1v = col_ptr[v + 1];                                  \
    float s2v = s2pb[v];                                                        \
    for (int base = p0; base < p1v; base += 64) {                               \
      int idx = base + lane;                                                    \
      int u = 0;                                                                \
      float cf = 0.f;                                                           \
      if (idx < p1v) {                                                          \
        u = csr_src[idx];                                                       \
        float2 pk = pack[u];                                                    \
        cf = fast_tanh(pk.x + s2v) * pk.y * ndv;                                \
      }                                                                         \
      int cnt = p1v - base;                                                     \
      if (cnt > 64) cnt = 64;                                                   \
      int j = 0;                                                                \
      for (; j + 8 <= cnt; j += 8) {                                            \
        int u0 = __shfl(u, j + 0), u1 = __shfl(u, j + 1);                       \
        int u2 = __shfl(u, j + 2), u3 = __shfl(u, j + 3);                       \
        int u4 = __shfl(u, j + 4), u5 = __shfl(u, j + 5);                       \
        int u6 = __shfl(u, j + 6), u7 = __shfl(u, j + 7);                       \
        unsigned t0 = *(const unsigned*)&HSRC_[(size_t)u0 * H_DIM + lane * 2];  \
        unsigned t1 = *(const unsigned*)&HSRC_[(size_t)u1 * H_DIM + lane * 2];  \
        unsigned t2 = *(const unsigned*)&HSRC_[(size_t)u2 * H_DIM + lane * 2];  \
        unsigned t3 = *(const unsigned*)&HSRC_[(size_t)u3 * H_DIM + lane * 2];  \
        unsigned t4 = *(const unsigned*)&HSRC_[(size_t)u4 * H_DIM + lane * 2];  \
        unsigned t5 = *(const unsigned*)&HSRC_[(size_t)u5 * H_DIM + lane * 2];  \
        unsigned t6 = *(const unsigned*)&HSRC_[(size_t)u6 * H_DIM + lane * 2];  \
        unsigned t7 = *(const unsigned*)&HSRC_[(size_t)u7 * H_DIM + lane * 2];  \
        float c0 = __shfl(cf, j + 0), c1 = __shfl(cf, j + 1);                   \
        float c2 = __shfl(cf, j + 2), c3 = __shfl(cf, j + 3);                   \
        float c4 = __shfl(cf, j + 4), c5 = __shfl(cf, j + 5);                   \
        float c6 = __shfl(cf, j + 6), c7 = __shfl(cf, j + 7);                   \
        ax = fmaf(c0, bflo(t0), ax); ay = fmaf(c0, bfhi(t0), ay);               \
        ax = fmaf(c1, bflo(t1), ax); ay = fmaf(c1, bfhi(t1), ay);               \
        ax = fmaf(c2, bflo(t2), ax); ay = fmaf(c2, bfhi(t2), ay);               \
        ax = fmaf(c3, bflo(t3), ax); ay = fmaf(c3, bfhi(t3), ay);               \
        ax = fmaf(c4, bflo(t4), ax); ay = fmaf(c4, bfhi(t4), ay);               \
        ax = fmaf(c5, bflo(t5), ax); ay = fmaf(c5, bfhi(t5), ay);               \
        ax = fmaf(c6, bflo(t6), ax); ay = fmaf(c6, bfhi(t6), ay);               \
        ax = fmaf(c7, bflo(t7), ax); ay = fmaf(c7, bfhi(t7), ay);               \
      }                                                                         \
      for (; j + 4 <= cnt; j += 4) {                                            \
        int u0 = __shfl(u, j + 0), u1 = __shfl(u, j + 1);                       \
        int u2 = __shfl(u, j + 2), u3 = __shfl(u, j + 3);                       \
        unsigned t0 = *(const unsigned*)&HSRC_[(size_t)u0 * H_DIM + lane * 2];  \
        unsigned t1 = *(const unsigned*)&HSRC_[(size_t)u1 * H_DIM + lane * 2];  \
        unsigned t2 = *(const unsigned*)&HSRC_[(size_t)u2 * H_DIM + lane * 2];  \
        unsigned t3 = *(const unsigned*)&HSRC_[(size_t)u3 * H_DIM + lane * 2];  \
        float c0 = __shfl(cf, j + 0), c1 = __shfl(cf, j + 1);                   \
        float c2 = __shfl(cf, j + 2), c3 = __shfl(cf, j + 3);                   \
        ax = fmaf(c0, bflo(t0), ax); ay = fmaf(c0, bfhi(t0), ay);               \
        ax = fmaf(c1, bflo(t1), ax); ay = fmaf(c1, bfhi(t1), ay);               \
        ax = fmaf(c2, bflo(t2), ax); ay = fmaf(c2, bfhi(t2), ay);               \
        ax = fmaf(c3, bflo(t3), ax); ay = fmaf(c3, bfhi(t3), ay);               \
      }                                                                         \
      for (; j < cnt; ++j) {                                                    \
        int uj = __shfl(u, j);                                                  \
        float cj = __shfl(cf, j);                                               \
        unsigned tj = *(const unsigned*)&HSRC_[(size_t)uj * H_DIM + lane * 2];  \
        ax = fmaf(cj, bflo(tj), ax); ay = fmaf(cj, bfhi(tj), ay);               \
      }                                                                         \
    }                                                                           \
  }

// agg layer 1: h1 = EPS*h0 + agg(h0); fused gate1 -> pack1, s2b.  Zero LDS.
__global__ __launch_bounds__(256) void agg1(const ushort_t* __restrict__ hbf,
    const float2* __restrict__ pack, const float* __restrict__ s2pb,
    const float* __restrict__ nd, const int* __restrict__ col_ptr,
    const int* __restrict__ csr_src, ushort_t* __restrict__ houtbf,
    const float* __restrict__ gwl, const float* __restrict__ gb1,
    float2* __restrict__ packo, float* __restrict__ s2o, int N) {
  int t = threadIdx.x;
  int v = blockIdx.x * 4 + (t >> 6);
  int lane = t & 63;
  if (v >= N) return;
  float ndv = nd[v];
  unsigned rv = *(const unsigned*)&hbf[(size_t)v * H_DIM + lane * 2];  // raw = h0
  AGG_CORE(hbf)
  float ox = fmaf(EPS_F, bflo(rv), ax);
  float oy = fmaf(EPS_F, bfhi(rv), ay);
  *(unsigned*)&houtbf[(size_t)v * H_DIM + lane * 2] = pack2bf(ox, oy);
  float2 g1 = *(const float2*)&gwl[lane * 2];
  float2 g2 = *(const float2*)&gwl[H_DIM + lane * 2];
  float q1 = ox * g1.x + oy * g1.y;
  float q2 = ox * g2.x + oy * g2.y;
#pragma unroll
  for (int off = 32; off > 0; off >>= 1) {
    q1 += __shfl_xor(q1, off);
    q2 += __shfl_xor(q2, off);
  }
  if (lane == 0) {
    packo[v] = make_float2(q1, ndv);
    s2o[v] = q2 + gb1[0];
  }
}

// agg layer 2 + fused gemm2 + log_softmax (R8 form, float4 weight staging)
__global__ __launch_bounds__(256) void agg2(const ushort_t* __restrict__ hbf,
    const ushort_t* __restrict__ rawbf, const float2* __restrict__ pack,
    const float* __restrict__ s2pb, const float* __restrict__ nd,
    const int* __restrict__ col_ptr, const int* __restrict__ csr_src,
    const float* __restrict__ w2, const float* __restrict__ b2,
    float* __restrict__ out, int N) {
  __shared__ float ws[C_DIM][129];
  __shared__ float bsh[C_DIM];
  __shared__ float hsm[4][H_DIM];
  int t = threadIdx.x;
  // float4 staging: 1280 float4 over 256 threads
  for (int i = t; i < (C_DIM * H_DIM) / 4; i += 256) {
    f32x4 vv = *(const f32x4*)&w2[i * 4];
    int rowi = i / 32, coli = (i % 32) * 4;
    ws[rowi][coli + 0] = vv[0];
    ws[rowi][coli + 1] = vv[1];
    ws[rowi][coli + 2] = vv[2];
    ws[rowi][coli + 3] = vv[3];
  }
  if (t < C_DIM) bsh[t] = b2[t];
  __syncthreads();
  int wave = t >> 6, lane = t & 63;
  int v = blockIdx.x * 4 + wave;
  bool act = v < N;
  if (act) {
    float ndv = nd[v];
    unsigned rv = *(const unsigned*)&rawbf[(size_t)v * H_DIM + lane * 2];
    AGG_CORE(hbf)
    float ox = fmaf(EPS_F, bflo(rv), ax);
    float oy = fmaf(EPS_F, bfhi(rv), ay);
    hsm[wave][lane * 2] = ox;
    hsm[wave][lane * 2 + 1] = oy;
  }
  __syncthreads();
  float accv = 0.f;
  if (act && lane < C_DIM) {
#pragma unroll 8
    for (int k = 0; k < H_DIM; ++k)
      accv = fmaf(hsm[wave][k], ws[lane][k], accv);
    accv += bsh[lane];
  }
  float m = (lane < C_DIM) ? accv : -1e30f;
#pragma unroll
  for (int off = 32; off > 0; off >>= 1) m = fmaxf(m, __shfl_xor(m, off));
  float ex = (lane < C_DIM) ? expf(accv - m) : 0.f;
  float s = ex;
#pragma unroll
  for (int off = 32; off > 0; off >>= 1) s += __shfl_xor(s, off);
  float lse = m + logf(s);
  if (act && lane < C_DIM) out[(size_t)v * C_DIM + lane] = accv - lse;
}

// ---------------- launch ----------------

extern "C" void kernel_launch(void* const* d_in, const int* in_sizes, int n_in,
                              void* d_out, int out_size, void* d_ws, size_t ws_size,
                              hipStream_t stream) {
  const float* x   = (const float*)d_in[0];
  const float* t1w = (const float*)d_in[1];
  const float* t1b = (const float*)d_in[2];
  const float* t2w = (const float*)d_in[3];
  const float* t2b = (const float*)d_in[4];
  const float* gw  = (const float*)d_in[5];
  const float* gb  = (const float*)d_in[6];
  const int*   ei  = (const int*)d_in[7];
  const int N = in_sizes[0] / F_DIM;
  const int E = in_sizes[7] / 2;
  float* out = (float*)d_out;

  char* p = (char*)d_ws;
  auto take = [&](size_t bytes) {
    char* r = p;
    p += (bytes + 255) & ~(size_t)255;
    return r;
  };
  ushort_t* h0 = (ushort_t*)take((size_t)N * H_DIM * 2);
  ushort_t* h1 = (ushort_t*)take((size_t)N * H_DIM * 2);
  float2* pack0 = (float2*)take((size_t)N * 8);
  float2* pack1 = (float2*)take((size_t)N * 8);
  float* s2a = (float*)take((size_t)N * 4);
  float* s2b = (float*)take((size_t)N * 4);
  float* nd  = (float*)take((size_t)N * 4);
  int* col_ptr = (int*)take((size_t)(N + 1) * 4);
  int* csr_src = (int*)take((size_t)E * 4);

  const int nbkt = (N + 255) >> 8;              // 196
  const int chunk = (E + NBLK - 1) / NBLK;      // 3125

  int* blkhist = (int*)take((size_t)2 * nbkt * NBLK * 4);
  int* bktbase = (int*)take((size_t)(2 * nbkt + 1) * 4);
  unsigned* colpart = (unsigned*)take((size_t)E * 4);
  uchar_t* rowpart  = (uchar_t*)take((size_t)E);

  const int* row = ei;
  const int* col = ei + E;

  part_count<<<NBLK, 256, 0, stream>>>(row, col, blkhist, E, nbkt, chunk);
  part_scatter<<<NBLK, 256, 0, stream>>>(row, col, blkhist, bktbase, colpart, rowpart, E, nbkt, chunk);
  bucket_both<<<2 * nbkt, 256, 0, stream>>>(colpart, rowpart, bktbase, col_ptr, csr_src, nd, N, E, nbkt);

  gemm1_mfma<<<(N + 63) / 64, 256, 0, stream>>>(x, t1w, t1b, gw, gb, nd, h0, pack0, s2a, N);

  int nwb = (N + 3) / 4;
  agg1<<<nwb, 256, 0, stream>>>(h0, pack0, s2a, nd, col_ptr, csr_src, h1,
                                gw + 2 * H_DIM, gb + 1, pack1, s2b, N);
  agg2<<<nwb, 256, 0, stream>>>(h1, h0, pack1, s2b, nd, col_ptr, csr_src,
                                t2w, t2b, out, N);
}